// Round 1
// baseline (1324.297 us; speedup 1.0000x reference)
//
#include <hip/hip_runtime.h>
#include <math.h>

#define BB 8
#define CC 32
#define TT 9
#define LL 512
#define HH 8
#define DD 4
#define NBT (BB*TT)          // 72
#define RELN (2*LL-1)        // 1023

// ---------------- mixed bias: mb[Ho][idx] = sum_h rpb[h][idx] * Wl[h][Ho] ----------------
__global__ void mixed_bias_kernel(const float* __restrict__ rpb,
                                  const float* __restrict__ Wl,
                                  float* __restrict__ mb) {
  int idx = blockIdx.x * blockDim.x + threadIdx.x;
  if (idx >= RELN) return;
  float r[HH];
  #pragma unroll
  for (int h = 0; h < HH; ++h) r[h] = rpb[h*RELN + idx];
  #pragma unroll
  for (int Ho = 0; Ho < HH; ++Ho) {
    float acc = 0.f;
    #pragma unroll
    for (int h = 0; h < HH; ++h) acc += r[h] * Wl[h*HH + Ho];
    mb[Ho*RELN + idx] = acc;
  }
}

// ---------------- transpose pl_w (512x512): outT[l][l'] = in[l'][l] ----------------
__global__ __launch_bounds__(256) void transpose512_kernel(const float* __restrict__ in,
                                                           float* __restrict__ outT) {
  __shared__ float tile[32][33];
  int bx = blockIdx.x * 32, by = blockIdx.y * 32;
  int tx = threadIdx.x & 31, ty = threadIdx.x >> 5;   // 32x8
  #pragma unroll
  for (int yy = ty; yy < 32; yy += 8)
    tile[yy][tx] = in[(by + yy)*LL + bx + tx];
  __syncthreads();
  #pragma unroll
  for (int yy = ty; yy < 32; yy += 8)
    outT[(bx + yy)*LL + by + tx] = tile[tx][yy];
}

// ---------------- q/k/v projection + l2norm ----------------
// out layout: dst[(bt*HH + h)*(LL*DD) + l*DD + d]
__global__ __launch_bounds__(256) void proj_kernel(
    const float* __restrict__ x,
    const float* __restrict__ Wq, const float* __restrict__ bq,
    const float* __restrict__ Wk, const float* __restrict__ bk,
    const float* __restrict__ Wv, const float* __restrict__ bv,
    float* __restrict__ qo, float* __restrict__ ko, float* __restrict__ vo) {
  int g = blockIdx.x * 256 + threadIdx.x;    // 0..36863
  int l  = g & (LL-1);
  int bt = g >> 9;
  int b = bt / TT, t = bt - b*TT;

  float xv[CC];
  #pragma unroll
  for (int c = 0; c < CC; ++c)
    xv[c] = x[((b*CC + c)*TT + t)*LL + l];

  const float* Ws[3] = {Wq, Wk, Wv};
  const float* bs[3] = {bq, bk, bv};
  float* ds[3] = {qo, ko, vo};
  #pragma unroll
  for (int p = 0; p < 3; ++p) {
    const float* W = Ws[p];
    const float* bi = bs[p];
    float* dst = ds[p];
    #pragma unroll
    for (int h = 0; h < HH; ++h) {
      float yv[DD];
      #pragma unroll
      for (int d = 0; d < DD; ++d) {
        int co = h*DD + d;
        float acc = bi[co];
        #pragma unroll
        for (int ci = 0; ci < CC; ++ci) acc += xv[ci] * W[co*CC + ci];
        yv[d] = acc;
      }
      float n = sqrtf(yv[0]*yv[0] + yv[1]*yv[1] + yv[2]*yv[2] + yv[3]*yv[3]);
      float inv = 1.0f / fmaxf(n, 1e-12f);
      float4 o4 = make_float4(yv[0]*inv, yv[1]*inv, yv[2]*inv, yv[3]*inv);
      *reinterpret_cast<float4*>(&dst[(bt*HH + h)*(LL*DD) + l*DD]) = o4;
    }
  }
}

// ---------------- fused attention ----------------
// grid (72, 16), block 512.  lane owns j = lane + jj*64, jj=0..7.
__global__ __launch_bounds__(512) void attn_kernel(
    const float* __restrict__ q, const float* __restrict__ k, const float* __restrict__ v,
    const float* __restrict__ Wl, const float* __restrict__ Wc,
    const float* __restrict__ mb, float* __restrict__ xatt) {
  __shared__ float k_lds[HH*LL*DD];   // 64 KB
  __shared__ float v_lds[HH*LL*DD];   // 64 KB
  __shared__ float sWl[HH*HH];
  __shared__ float sWc[HH*HH];

  const int bt   = blockIdx.x;
  const int iblk = blockIdx.y;
  const int tid  = threadIdx.x;
  const int wave = tid >> 6;
  const int lane = tid & 63;

  {
    const float* kg = k + bt*(HH*LL*DD);
    const float* vg = v + bt*(HH*LL*DD);
    #pragma unroll
    for (int it = 0; it < 8; ++it) {
      int idx = (it*512 + tid) * 4;
      *reinterpret_cast<float4*>(&k_lds[idx]) = *reinterpret_cast<const float4*>(&kg[idx]);
      *reinterpret_cast<float4*>(&v_lds[idx]) = *reinterpret_cast<const float4*>(&vg[idx]);
    }
    if (tid < HH*HH) { sWl[tid] = 0.5f * Wl[tid]; sWc[tid] = Wc[tid]; }  // 0.5 = 1/sqrt(D)
  }
  __syncthreads();

  for (int r = 0; r < 4; ++r) {
    const int i = iblk*32 + wave*4 + r;

    // ---- scores s[h][jj] = q[h,i,:] . k[h,j,:]
    float s[HH][8];
    #pragma unroll
    for (int h = 0; h < HH; ++h) {
      float4 qh = *reinterpret_cast<const float4*>(&q[(bt*HH + h)*(LL*DD) + i*DD]);
      #pragma unroll
      for (int jj = 0; jj < 8; ++jj) {
        int j = lane + jj*64;
        float4 kv = *reinterpret_cast<const float4*>(&k_lds[(h*LL + j)*DD]);
        s[h][jj] = qh.x*kv.x + qh.y*kv.y + qh.z*kv.z + qh.w*kv.w;
      }
    }

    // ---- head-mix 1 (+ mixed rel-pos bias): lg[Ho][jj]
    float lg[HH][8];
    #pragma unroll
    for (int Ho = 0; Ho < HH; ++Ho) {
      #pragma unroll
      for (int jj = 0; jj < 8; ++jj) {
        int j = lane + jj*64;
        lg[Ho][jj] = mb[Ho*RELN + (i - j + (LL-1))];
      }
    }
    #pragma unroll
    for (int h = 0; h < HH; ++h) {
      #pragma unroll
      for (int Ho = 0; Ho < HH; ++Ho) {
        float w = sWl[h*HH + Ho];
        #pragma unroll
        for (int jj = 0; jj < 8; ++jj)
          lg[Ho][jj] += s[h][jj] * w;
      }
    }

    // ---- softmax over the 512 j per output-head row
    #pragma unroll
    for (int Ho = 0; Ho < HH; ++Ho) {
      float m = lg[Ho][0];
      #pragma unroll
      for (int jj = 1; jj < 8; ++jj) m = fmaxf(m, lg[Ho][jj]);
      #pragma unroll
      for (int off = 32; off >= 1; off >>= 1) m = fmaxf(m, __shfl_xor(m, off));
      float ssum = 0.f;
      #pragma unroll
      for (int jj = 0; jj < 8; ++jj) {
        float e = __expf(lg[Ho][jj] - m);
        lg[Ho][jj] = e;
        ssum += e;
      }
      #pragma unroll
      for (int off = 32; off >= 1; off >>= 1) ssum += __shfl_xor(ssum, off);
      float inv = 1.0f / ssum;
      #pragma unroll
      for (int jj = 0; jj < 8; ++jj) lg[Ho][jj] *= inv;
    }

    // ---- head-mix 2 + PV (two groups of 4 output heads to cap registers)
    float4 o4[HH];
    #pragma unroll
    for (int Ho = 0; Ho < HH; ++Ho) o4[Ho] = make_float4(0.f, 0.f, 0.f, 0.f);
    #pragma unroll
    for (int gph = 0; gph < 2; ++gph) {
      float a2[4][8];
      #pragma unroll
      for (int u = 0; u < 4; ++u)
        #pragma unroll
        for (int jj = 0; jj < 8; ++jj) a2[u][jj] = 0.f;
      #pragma unroll
      for (int h = 0; h < HH; ++h) {
        #pragma unroll
        for (int u = 0; u < 4; ++u) {
          float w = sWc[h*HH + gph*4 + u];
          #pragma unroll
          for (int jj = 0; jj < 8; ++jj) a2[u][jj] += lg[h][jj] * w;
        }
      }
      #pragma unroll
      for (int u = 0; u < 4; ++u) {
        int Ho = gph*4 + u;
        #pragma unroll
        for (int jj = 0; jj < 8; ++jj) {
          int j = lane + jj*64;
          float4 vv = *reinterpret_cast<const float4*>(&v_lds[(Ho*LL + j)*DD]);
          o4[Ho].x += a2[u][jj]*vv.x;
          o4[Ho].y += a2[u][jj]*vv.y;
          o4[Ho].z += a2[u][jj]*vv.z;
          o4[Ho].w += a2[u][jj]*vv.w;
        }
      }
    }

    // ---- cross-lane reduce (sum over j) and write row
    #pragma unroll
    for (int Ho = 0; Ho < HH; ++Ho) {
      float vx = o4[Ho].x, vy = o4[Ho].y, vz = o4[Ho].z, vw = o4[Ho].w;
      #pragma unroll
      for (int off = 32; off >= 1; off >>= 1) {
        vx += __shfl_xor(vx, off);
        vy += __shfl_xor(vy, off);
        vz += __shfl_xor(vz, off);
        vw += __shfl_xor(vw, off);
      }
      o4[Ho] = make_float4(vx, vy, vz, vw);
    }
    if (lane == 0) {
      #pragma unroll
      for (int Ho = 0; Ho < HH; ++Ho)
        *reinterpret_cast<float4*>(&xatt[(bt*LL + i)*CC + Ho*DD]) = o4[Ho];
    }
  }
}

// ---------------- Wm projection; t<8 -> final out, t==8 -> xm8 scratch ----------------
__global__ __launch_bounds__(256) void wm_kernel(
    const float* __restrict__ xatt, const float* __restrict__ Wm, const float* __restrict__ bm,
    float* __restrict__ out, float* __restrict__ xm8) {
  int g = blockIdx.x * 256 + threadIdx.x;
  int l  = g & (LL-1);
  int bt = g >> 9;
  int b = bt / TT, t = bt - b*TT;
  float xv[CC];
  #pragma unroll
  for (int c = 0; c < CC; c += 4) {
    float4 x4 = *reinterpret_cast<const float4*>(&xatt[g*CC + c]);
    xv[c] = x4.x; xv[c+1] = x4.y; xv[c+2] = x4.z; xv[c+3] = x4.w;
  }
  #pragma unroll
  for (int co = 0; co < CC; ++co) {
    float acc = bm[co];
    #pragma unroll
    for (int ci = 0; ci < CC; ++ci) acc += xv[ci] * Wm[co*CC + ci];
    if (t < TT-1) out[((b*CC + co)*TT + t)*LL + l] = acc;
    else          xm8[(b*CC + co)*LL + l] = acc;
  }
}

// ---------------- conv over (ci,t) + BN(eval) + ReLU ----------------
__global__ __launch_bounds__(512) void conv_kernel(
    const float* __restrict__ out, const float* __restrict__ pp,
    const float* __restrict__ cw, const float* __restrict__ cb,
    const float* __restrict__ bng, const float* __restrict__ bnb,
    float* __restrict__ yws) {
  int bc = blockIdx.x;            // b*32 + co
  int b = bc >> 5, co = bc & 31;
  int l = threadIdx.x;
  float acc = cb[co];
  #pragma unroll
  for (int ci = 0; ci < CC; ++ci) {
    const float* base = out + ((b*CC + ci)*TT)*LL + l;
    const float* w = cw + (co*CC + ci)*TT;
    #pragma unroll
    for (int t = 0; t < TT-1; ++t) acc += base[t*LL] * w[t];
    acc += pp[ci*LL + l] * w[TT-1];
  }
  // y/sqrt(1+1e-5) then y*g+b then relu
  float scale = bng[co] * 0.999995000037499687f;
  float val = acc * scale + bnb[co];
  yws[bc*LL + l] = fmaxf(val, 0.f);
}

// ---------------- token-linear p = y @ pl_w.T + pl_b; out[t=8] = xm8 - p ----------------
__global__ __launch_bounds__(512) void pl_kernel(
    const float* __restrict__ yws, const float* __restrict__ plwT,
    const float* __restrict__ plb, const float* __restrict__ xm8,
    float* __restrict__ out) {
  __shared__ float sy[2][LL];
  int bc0 = blockIdx.x * 2;
  int tid = threadIdx.x;
  sy[0][tid] = yws[bc0*LL + tid];
  sy[1][tid] = yws[(bc0+1)*LL + tid];
  __syncthreads();
  float acc0 = plb[tid], acc1 = plb[tid];
  #pragma unroll 4
  for (int l = 0; l < LL; ++l) {
    float w = plwT[l*LL + tid];
    acc0 += sy[0][l] * w;
    acc1 += sy[1][l] * w;
  }
  out[(bc0*TT + (TT-1))*LL + tid]       = xm8[bc0*LL + tid] - acc0;
  out[((bc0+1)*TT + (TT-1))*LL + tid]   = xm8[(bc0+1)*LL + tid] - acc1;
}

extern "C" void kernel_launch(void* const* d_in, const int* in_sizes, int n_in,
                              void* d_out, int out_size, void* d_ws, size_t ws_size,
                              hipStream_t stream) {
  const float* x    = (const float*)d_in[0];
  const float* Wq   = (const float*)d_in[1];
  const float* bq   = (const float*)d_in[2];
  const float* Wk   = (const float*)d_in[3];
  const float* bk   = (const float*)d_in[4];
  const float* Wv   = (const float*)d_in[5];
  const float* bv   = (const float*)d_in[6];
  const float* Wm   = (const float*)d_in[7];
  const float* bm   = (const float*)d_in[8];
  const float* Wl   = (const float*)d_in[9];
  const float* Wc   = (const float*)d_in[10];
  const float* rpb  = (const float*)d_in[11];
  const float* pp   = (const float*)d_in[12];
  const float* cw   = (const float*)d_in[13];
  const float* cb   = (const float*)d_in[14];
  const float* bng  = (const float*)d_in[15];
  const float* bnb  = (const float*)d_in[16];
  const float* plw  = (const float*)d_in[17];
  const float* plb  = (const float*)d_in[18];
  float* out = (float*)d_out;

  float* ws = (float*)d_ws;
  const size_t QKV = (size_t)NBT*HH*LL*DD;     // 1179648
  float* q_ws   = ws;                 // QKV
  float* k_ws   = q_ws + QKV;         // QKV
  float* v_ws   = k_ws + QKV;         // QKV
  float* xatt   = v_ws + QKV;         // NBT*LL*CC = 1179648
  float* xm8    = xatt + QKV;         // BB*CC*LL = 131072
  float* yws    = xm8 + (size_t)BB*CC*LL;      // 131072
  float* plwT   = yws + (size_t)BB*CC*LL;      // 262144
  float* mbias  = plwT + (size_t)LL*LL;        // 8184

  mixed_bias_kernel<<<2, 512, 0, stream>>>(rpb, Wl, mbias);
  transpose512_kernel<<<dim3(16,16), 256, 0, stream>>>(plw, plwT);
  proj_kernel<<<(BB*TT*LL)/256, 256, 0, stream>>>(x, Wq, bq, Wk, bk, Wv, bv, q_ws, k_ws, v_ws);
  attn_kernel<<<dim3(NBT, 16), 512, 0, stream>>>(q_ws, k_ws, v_ws, Wl, Wc, mbias, xatt);
  wm_kernel<<<(BB*TT*LL)/256, 256, 0, stream>>>(xatt, Wm, bm, out, xm8);
  conv_kernel<<<BB*CC, LL, 0, stream>>>(out, pp, cw, cb, bng, bnb, yws);
  pl_kernel<<<(BB*CC)/2, LL, 0, stream>>>(yws, plwT, plb, xm8, out);
}